// Round 3
// baseline (1620.626 us; speedup 1.0000x reference)
//
#include <hip/hip_runtime.h>
#include <hip/hip_bf16.h>

#define B_ 8
#define L_ 2048
#define DM 512
#define E_ 64
#define H_ 64
#define R_ 4
#define KC 3
#define BL (B_*L_)   // 16384
#define NX 132       // R + 2H

// ---- K1: xz = x @ W_in ; cols 0..63 -> xp_pre, 64..127 -> res
__global__ __launch_bounds__(256) void k_gemm_in(
    const float* __restrict__ x, const float* __restrict__ Win,
    float* __restrict__ xp_pre, float* __restrict__ res)
{
  __shared__ float As[32][33];
  __shared__ float Bs[32][128];
  const int m0 = blockIdx.x * 32;
  const int tid = threadIdx.x;
  const int ty4 = (tid >> 5) * 4;
  const int tx4 = (tid & 31) * 4;
  float acc[4][4] = {};
  for (int k0 = 0; k0 < DM; k0 += 32) {
    #pragma unroll
    for (int i = tid; i < 1024; i += 256) {
      int r = i >> 5, c = i & 31;
      As[c][r] = x[(size_t)(m0 + r) * DM + k0 + c];
    }
    #pragma unroll
    for (int i = tid; i < 4096; i += 256) {
      int r = i >> 7, c = i & 127;
      Bs[r][c] = Win[(size_t)(k0 + r) * 128 + c];
    }
    __syncthreads();
    #pragma unroll
    for (int kk = 0; kk < 32; ++kk) {
      float a[4], bb[4];
      #pragma unroll
      for (int i = 0; i < 4; ++i) a[i] = As[kk][ty4 + i];
      #pragma unroll
      for (int j = 0; j < 4; ++j) bb[j] = Bs[kk][tx4 + j];
      #pragma unroll
      for (int i = 0; i < 4; ++i)
        #pragma unroll
        for (int j = 0; j < 4; ++j)
          acc[i][j] = fmaf(a[i], bb[j], acc[i][j]);
    }
    __syncthreads();
  }
  #pragma unroll
  for (int i = 0; i < 4; ++i) {
    size_t m = m0 + ty4 + i;
    #pragma unroll
    for (int j = 0; j < 4; ++j) {
      int c = tx4 + j;
      if (c < 64) xp_pre[m * 64 + c] = acc[i][j];
      else        res[m * 64 + (c - 64)] = acc[i][j];
    }
  }
}

// ---- K2: causal dwconv(K=3)+silu -> xp ; x_dbl = xp @ W_x ; delta = softplus(dlt@W_dt + b_dt)
__global__ __launch_bounds__(192) void k_xdbl(
    const float* __restrict__ xp_pre,
    const float* __restrict__ conv_w, const float* __restrict__ conv_b,
    const float* __restrict__ Wx, const float* __restrict__ Wdt, const float* __restrict__ bdt,
    float* __restrict__ xp, float* __restrict__ Bm, float* __restrict__ Cm,
    float* __restrict__ delta)
{
  __shared__ float xps[64];
  __shared__ float dlts[4];
  const int token = blockIdx.x;
  const int b = token / L_, l = token % L_;
  const int tid = threadIdx.x;
  if (tid < 64) {
    float acc = conv_b[tid];
    #pragma unroll
    for (int j = 0; j < KC; ++j) {
      int ll = l - (KC - 1) + j;
      if (ll >= 0)
        acc = fmaf(xp_pre[((size_t)b * L_ + ll) * 64 + tid], conv_w[tid * KC + j], acc);
    }
    float v = acc / (1.0f + __expf(-acc));   // silu
    xps[tid] = v;
    xp[(size_t)token * 64 + tid] = v;
  }
  __syncthreads();
  if (tid < NX) {
    float acc = 0.f;
    #pragma unroll 8
    for (int e = 0; e < 64; ++e)
      acc = fmaf(xps[e], Wx[e * NX + tid], acc);
    if (tid < R_) dlts[tid] = acc;
    else if (tid < R_ + H_) Bm[(size_t)token * 64 + (tid - R_)] = acc;
    else Cm[(size_t)token * 64 + (tid - R_ - H_)] = acc;
  }
  __syncthreads();
  if (tid < 64) {
    float d = bdt[tid];
    #pragma unroll
    for (int r = 0; r < R_; ++r)
      d = fmaf(dlts[r], Wdt[r * 64 + tid], d);
    float sp = (d > 20.f) ? d : log1pf(__expf(d));   // softplus
    delta[(size_t)token * 64 + tid] = sp;
  }
}

// ---- K3: selective scan. 1 wave per (b,e), lane = h.
__global__ __launch_bounds__(64) void k_scan(
    const float* __restrict__ delta, const float* __restrict__ Bm, const float* __restrict__ Cm,
    const float* __restrict__ xp, const float* __restrict__ res,
    const float* __restrict__ A_log, const float* __restrict__ Dp,
    float* __restrict__ yg)
{
  const int b = blockIdx.x >> 6;
  const int e = blockIdx.x & 63;
  const int h = threadIdx.x;
  const float A = -__expf(A_log[e * 64 + h]);
  const float Dv = Dp[e];
  float s = 0.f;
  const size_t base = (size_t)b * L_ * 64;
  #pragma unroll 4
  for (int l = 0; l < L_; ++l) {
    const size_t off = base + (size_t)l * 64;
    float dlt = delta[off + e];
    float xv  = xp[off + e];
    float rv  = res[off + e];
    float Bh  = Bm[off + h];
    float Ch  = Cm[off + h];
    float dA  = __expf(dlt * A);
    s = fmaf(dA, s, dlt * Bh * xv);
    float p = s * Ch;
    #pragma unroll
    for (int o = 32; o > 0; o >>= 1) p += __shfl_xor(p, o, 64);
    if (h == 0) {
      float y = fmaf(xv, Dv, p);
      y *= 1.0f / (1.0f + __expf(-rv));   // * sigmoid(res)
      yg[off + e] = y;
    }
  }
}

// ---- K4: out = yg @ W_out  (16384x64 @ 64x512), 4 tokens per block
__global__ __launch_bounds__(256) void k_gemm_out(
    const float* __restrict__ yg, const float* __restrict__ Wout,
    float* __restrict__ out)
{
  __shared__ float ys[4][64];
  const int t0 = blockIdx.x * 4;
  const int tid = threadIdx.x;
  {
    int t = tid >> 6, k = tid & 63;
    ys[t][k] = yg[(size_t)(t0 + t) * 64 + k];
  }
  __syncthreads();
  float acc[4][2] = {};
  for (int k = 0; k < 64; ++k) {
    float w0 = Wout[k * DM + tid];
    float w1 = Wout[k * DM + tid + 256];
    #pragma unroll
    for (int t = 0; t < 4; ++t) {
      acc[t][0] = fmaf(ys[t][k], w0, acc[t][0]);
      acc[t][1] = fmaf(ys[t][k], w1, acc[t][1]);
    }
  }
  #pragma unroll
  for (int t = 0; t < 4; ++t) {
    out[(size_t)(t0 + t) * DM + tid]       = acc[t][0];
    out[(size_t)(t0 + t) * DM + tid + 256] = acc[t][1];
  }
}

extern "C" void kernel_launch(void* const* d_in, const int* in_sizes, int n_in,
                              void* d_out, int out_size, void* d_ws, size_t ws_size,
                              hipStream_t stream) {
  const float* x      = (const float*)d_in[0];
  const float* Win    = (const float*)d_in[1];
  const float* conv_w = (const float*)d_in[2];
  const float* conv_b = (const float*)d_in[3];
  const float* Wx     = (const float*)d_in[4];
  const float* Wdt    = (const float*)d_in[5];
  const float* bdt    = (const float*)d_in[6];
  const float* A_log  = (const float*)d_in[7];
  const float* Dp     = (const float*)d_in[8];
  const float* Wout   = (const float*)d_in[9];
  float* out = (float*)d_out;

  float* ws = (float*)d_ws;
  const size_t SZ = (size_t)BL * 64;
  float* xp_pre = ws;
  float* res    = ws + 1 * SZ;
  float* xp     = ws + 2 * SZ;
  float* Bm     = ws + 3 * SZ;
  float* Cm     = ws + 4 * SZ;
  float* delta  = ws + 5 * SZ;
  float* yg     = ws + 6 * SZ;

  hipLaunchKernelGGL(k_gemm_in,  dim3(BL / 32), dim3(256), 0, stream,
                     x, Win, xp_pre, res);
  hipLaunchKernelGGL(k_xdbl,     dim3(BL),      dim3(192), 0, stream,
                     xp_pre, conv_w, conv_b, Wx, Wdt, bdt, xp, Bm, Cm, delta);
  hipLaunchKernelGGL(k_scan,     dim3(B_ * E_), dim3(64),  0, stream,
                     delta, Bm, Cm, xp, res, A_log, Dp, yg);
  hipLaunchKernelGGL(k_gemm_out, dim3(BL / 4),  dim3(256), 0, stream,
                     yg, Wout, out);
}

// Round 4
// 381.565 us; speedup vs baseline: 4.2473x; 4.2473x over previous
//
#include <hip/hip_runtime.h>
#include <hip/hip_bf16.h>

#define B_ 8
#define L_ 2048
#define DM 512
#define E_ 64
#define H_ 64
#define R_ 4
#define KC 3
#define BL (B_*L_)   // 16384
#define NX 132       // R + 2H
#define LC 128       // scan chunk length
#define NCH (L_/LC)  // 16 chunks

// ---- K1: xz = x @ W_in ; cols 0..63 -> xp_pre, 64..127 -> res
__global__ __launch_bounds__(256) void k_gemm_in(
    const float* __restrict__ x, const float* __restrict__ Win,
    float* __restrict__ xp_pre, float* __restrict__ res)
{
  __shared__ float As[32][33];
  __shared__ float Bs[32][128];
  const int m0 = blockIdx.x * 32;
  const int tid = threadIdx.x;
  const int ty4 = (tid >> 5) * 4;
  const int tx4 = (tid & 31) * 4;
  float acc[4][4] = {};
  for (int k0 = 0; k0 < DM; k0 += 32) {
    #pragma unroll
    for (int i = tid; i < 1024; i += 256) {
      int r = i >> 5, c = i & 31;
      As[c][r] = x[(size_t)(m0 + r) * DM + k0 + c];
    }
    #pragma unroll
    for (int i = tid; i < 4096; i += 256) {
      int r = i >> 7, c = i & 127;
      Bs[r][c] = Win[(size_t)(k0 + r) * 128 + c];
    }
    __syncthreads();
    #pragma unroll
    for (int kk = 0; kk < 32; ++kk) {
      float a[4], bb[4];
      #pragma unroll
      for (int i = 0; i < 4; ++i) a[i] = As[kk][ty4 + i];
      #pragma unroll
      for (int j = 0; j < 4; ++j) bb[j] = Bs[kk][tx4 + j];
      #pragma unroll
      for (int i = 0; i < 4; ++i)
        #pragma unroll
        for (int j = 0; j < 4; ++j)
          acc[i][j] = fmaf(a[i], bb[j], acc[i][j]);
    }
    __syncthreads();
  }
  #pragma unroll
  for (int i = 0; i < 4; ++i) {
    size_t m = m0 + ty4 + i;
    #pragma unroll
    for (int j = 0; j < 4; ++j) {
      int c = tx4 + j;
      if (c < 64) xp_pre[m * 64 + c] = acc[i][j];
      else        res[m * 64 + (c - 64)] = acc[i][j];
    }
  }
}

// ---- K2: causal dwconv(K=3)+silu -> xp ; x_dbl = xp @ W_x ; delta = softplus(dlt@W_dt + b_dt)
__global__ __launch_bounds__(192) void k_xdbl(
    const float* __restrict__ xp_pre,
    const float* __restrict__ conv_w, const float* __restrict__ conv_b,
    const float* __restrict__ Wx, const float* __restrict__ Wdt, const float* __restrict__ bdt,
    float* __restrict__ xp, float* __restrict__ Bm, float* __restrict__ Cm,
    float* __restrict__ delta)
{
  __shared__ float xps[64];
  __shared__ float dlts[4];
  const int token = blockIdx.x;
  const int b = token / L_, l = token % L_;
  const int tid = threadIdx.x;
  if (tid < 64) {
    float acc = conv_b[tid];
    #pragma unroll
    for (int j = 0; j < KC; ++j) {
      int ll = l - (KC - 1) + j;
      if (ll >= 0)
        acc = fmaf(xp_pre[((size_t)b * L_ + ll) * 64 + tid], conv_w[tid * KC + j], acc);
    }
    float v = acc / (1.0f + __expf(-acc));   // silu
    xps[tid] = v;
    xp[(size_t)token * 64 + tid] = v;
  }
  __syncthreads();
  if (tid < NX) {
    float acc = 0.f;
    #pragma unroll 8
    for (int e = 0; e < 64; ++e)
      acc = fmaf(xps[e], Wx[e * NX + tid], acc);
    if (tid < R_) dlts[tid] = acc;
    else if (tid < R_ + H_) Bm[(size_t)token * 64 + (tid - R_)] = acc;
    else Cm[(size_t)token * 64 + (tid - R_ - H_)] = acc;
  }
  __syncthreads();
  if (tid < 64) {
    float d = bdt[tid];
    #pragma unroll
    for (int r = 0; r < R_; ++r)
      d = fmaf(dlts[r], Wdt[r * 64 + tid], d);
    float sp = (d > 20.f) ? d : log1pf(__expf(d));   // softplus
    delta[(size_t)token * 64 + tid] = sp;
  }
}

// ---- K3a: per-chunk summaries. block = (b,e,c), lane = h.
// Ssum = chunk-local end state (from s_in = 0); Pp = exp(A_h * sum(delta)) = chunk decay.
__global__ __launch_bounds__(64) void k_scan1(
    const float* __restrict__ delta, const float* __restrict__ Bm, const float* __restrict__ xp,
    const float* __restrict__ A_log,
    float* __restrict__ Ssum, float* __restrict__ Pp)
{
  const int blk = blockIdx.x;
  const int c = blk & (NCH - 1);
  const int e = (blk >> 4) & 63;
  const int b = blk >> 10;
  const int h = threadIdx.x;
  const float A = -__expf(A_log[e * 64 + h]);
  float s = 0.f, sd = 0.f;
  const int l0 = c * LC;
  #pragma unroll 4
  for (int k = 0; k < LC; ++k) {
    const size_t off = ((size_t)b * L_ + (l0 + k)) * 64;
    float dlt = delta[off + e];
    float xv  = xp[off + e];
    float Bh  = Bm[off + h];
    float dA  = __expf(dlt * A);
    s = fmaf(dA, s, dlt * Bh * xv);
    sd += dlt;
  }
  const size_t idx = (size_t)blk * 64 + h;
  Ssum[idx] = s;
  Pp[idx]   = __expf(A * sd);
}

// ---- K3b: compose chunk summaries -> entry state per chunk. block = (b,e), lane = h.
__global__ __launch_bounds__(64) void k_scan2(
    const float* __restrict__ Ssum, const float* __restrict__ Pp,
    float* __restrict__ Sin)
{
  const int blk = blockIdx.x;         // b*64 + e
  const int h = threadIdx.x;
  float s_in = 0.f;
  #pragma unroll
  for (int c = 0; c < NCH; ++c) {
    const size_t idx = ((size_t)blk * NCH + c) * 64 + h;
    Sin[idx] = s_in;
    s_in = fmaf(Pp[idx], s_in, Ssum[idx]);
  }
}

// ---- K3c: full scan per chunk from entry state; LDS-transpose reduction for y.
__global__ __launch_bounds__(64) void k_scan3(
    const float* __restrict__ delta, const float* __restrict__ Bm, const float* __restrict__ Cm,
    const float* __restrict__ xp, const float* __restrict__ res,
    const float* __restrict__ A_log, const float* __restrict__ Dp,
    const float* __restrict__ Sin,
    float* __restrict__ yg)
{
  __shared__ float tile[64 * 65];
  const int blk = blockIdx.x;
  const int c = blk & (NCH - 1);
  const int e = (blk >> 4) & 63;
  const int b = blk >> 10;
  const int h = threadIdx.x;
  const float A = -__expf(A_log[e * 64 + h]);
  const float Dv = Dp[e];
  float s = Sin[(size_t)blk * 64 + h];
  #pragma unroll
  for (int sub = 0; sub < LC / 64; ++sub) {
    const int l0 = c * LC + sub * 64;
    float xk = 0.f, rk = 0.f;
    #pragma unroll 4
    for (int k = 0; k < 64; ++k) {
      const size_t off = ((size_t)b * L_ + (l0 + k)) * 64;
      float dlt = delta[off + e];
      float xv  = xp[off + e];
      float rv  = res[off + e];
      float Bh  = Bm[off + h];
      float Ch  = Cm[off + h];
      float dA  = __expf(dlt * A);
      s = fmaf(dA, s, dlt * Bh * xv);
      tile[k * 65 + h] = s * Ch;
      xk = (h == k) ? xv : xk;
      rk = (h == k) ? rv : rk;
    }
    __syncthreads();
    // lane t (=h) reduces row t over all 64 h-slots; stride 65 -> conflict-free
    float a0 = 0.f, a1 = 0.f, a2 = 0.f, a3 = 0.f;
    #pragma unroll
    for (int j = 0; j < 64; j += 4) {
      a0 += tile[h * 65 + j];
      a1 += tile[h * 65 + j + 1];
      a2 += tile[h * 65 + j + 2];
      a3 += tile[h * 65 + j + 3];
    }
    float sum = (a0 + a1) + (a2 + a3);
    float y = fmaf(xk, Dv, sum);
    y *= 1.0f / (1.0f + __expf(-rk));      // * sigmoid(res)
    yg[((size_t)b * L_ + (l0 + h)) * 64 + e] = y;
    __syncthreads();
  }
}

// ---- K4: out = yg @ W_out  (16384x64 @ 64x512), 4 tokens per block
__global__ __launch_bounds__(256) void k_gemm_out(
    const float* __restrict__ yg, const float* __restrict__ Wout,
    float* __restrict__ out)
{
  __shared__ float ys[4][64];
  const int t0 = blockIdx.x * 4;
  const int tid = threadIdx.x;
  {
    int t = tid >> 6, k = tid & 63;
    ys[t][k] = yg[(size_t)(t0 + t) * 64 + k];
  }
  __syncthreads();
  float acc[4][2] = {};
  for (int k = 0; k < 64; ++k) {
    float w0 = Wout[k * DM + tid];
    float w1 = Wout[k * DM + tid + 256];
    #pragma unroll
    for (int t = 0; t < 4; ++t) {
      acc[t][0] = fmaf(ys[t][k], w0, acc[t][0]);
      acc[t][1] = fmaf(ys[t][k], w1, acc[t][1]);
    }
  }
  #pragma unroll
  for (int t = 0; t < 4; ++t) {
    out[(size_t)(t0 + t) * DM + tid]       = acc[t][0];
    out[(size_t)(t0 + t) * DM + tid + 256] = acc[t][1];
  }
}

extern "C" void kernel_launch(void* const* d_in, const int* in_sizes, int n_in,
                              void* d_out, int out_size, void* d_ws, size_t ws_size,
                              hipStream_t stream) {
  const float* x      = (const float*)d_in[0];
  const float* Win    = (const float*)d_in[1];
  const float* conv_w = (const float*)d_in[2];
  const float* conv_b = (const float*)d_in[3];
  const float* Wx     = (const float*)d_in[4];
  const float* Wdt    = (const float*)d_in[5];
  const float* bdt    = (const float*)d_in[6];
  const float* A_log  = (const float*)d_in[7];
  const float* Dp     = (const float*)d_in[8];
  const float* Wout   = (const float*)d_in[9];
  float* out = (float*)d_out;

  float* ws = (float*)d_ws;
  const size_t SZ = (size_t)BL * 64;       // 1M floats = 4 MB
  float* xp_pre = ws;
  float* res    = ws + 1 * SZ;
  float* xp     = ws + 2 * SZ;
  float* Bm     = ws + 3 * SZ;
  float* Cm     = ws + 4 * SZ;
  float* delta  = ws + 5 * SZ;
  float* yg     = ws + 6 * SZ;
  const size_t CH = (size_t)B_ * E_ * NCH * 64;   // 512K floats = 2 MB
  float* Ssum   = ws + 7 * SZ;
  float* Pp     = ws + 7 * SZ + 1 * CH;
  float* Sin    = ws + 7 * SZ + 2 * CH;

  hipLaunchKernelGGL(k_gemm_in,  dim3(BL / 32), dim3(256), 0, stream,
                     x, Win, xp_pre, res);
  hipLaunchKernelGGL(k_xdbl,     dim3(BL),      dim3(192), 0, stream,
                     xp_pre, conv_w, conv_b, Wx, Wdt, bdt, xp, Bm, Cm, delta);
  hipLaunchKernelGGL(k_scan1,    dim3(B_ * E_ * NCH), dim3(64), 0, stream,
                     delta, Bm, xp, A_log, Ssum, Pp);
  hipLaunchKernelGGL(k_scan2,    dim3(B_ * E_), dim3(64), 0, stream,
                     Ssum, Pp, Sin);
  hipLaunchKernelGGL(k_scan3,    dim3(B_ * E_ * NCH), dim3(64), 0, stream,
                     delta, Bm, Cm, xp, res, A_log, Dp, Sin, yg);
  hipLaunchKernelGGL(k_gemm_out, dim3(BL / 4),  dim3(256), 0, stream,
                     yg, Wout, out);
}

// Round 5
// 244.211 us; speedup vs baseline: 6.6362x; 1.5624x over previous
//
#include <hip/hip_runtime.h>
#include <hip/hip_bf16.h>

#define B_ 8
#define L_ 2048
#define DM 512
#define E_ 64
#define H_ 64
#define R_ 4
#define KC 3
#define BL (B_*L_)   // 16384
#define NX 132       // R + 2H
#define LC 128       // scan chunk length
#define NCH (L_/LC)  // 16 chunks

// ---- K0: fold W_dt into W_x -> WF[64][192]: cols 0..63 = W_x[:,:4]@W_dt, 64..127 = B-part, 128..191 = C-part
__global__ __launch_bounds__(192) void k_wfuse(
    const float* __restrict__ Wx, const float* __restrict__ Wdt,
    float* __restrict__ WF)
{
  const int r = blockIdx.x;       // 0..63
  const int c = threadIdx.x;      // 0..191
  float v;
  if (c < 64) {
    v = 0.f;
    #pragma unroll
    for (int j = 0; j < R_; ++j)
      v = fmaf(Wx[r * NX + j], Wdt[j * 64 + c], v);
  } else if (c < 128) {
    v = Wx[r * NX + R_ + (c - 64)];
  } else {
    v = Wx[r * NX + R_ + 64 + (c - 128)];
  }
  WF[r * 192 + c] = v;
}

// ---- K1: xz = x @ W_in ; cols 0..63 -> xp_pre[token][64], 64..127 -> resT[b*64+c][L]
__global__ __launch_bounds__(256) void k_gemm_in(
    const float* __restrict__ x, const float* __restrict__ Win,
    float* __restrict__ xp_pre, float* __restrict__ resT)
{
  __shared__ float As[32][36];    // [k][m], 144B rows (16B aligned)
  __shared__ float Bs[32][128];
  const int m0 = blockIdx.x * 32;
  const int tid = threadIdx.x;
  const int ty4 = (tid >> 5) * 4;
  const int tx4 = (tid & 31) * 4;
  const int arow = tid >> 3;      // 0..31
  const int acg  = tid & 7;       // 0..7
  float acc[4][4] = {};
  for (int k0 = 0; k0 < DM; k0 += 32) {
    float4 av = *(const float4*)&x[(size_t)(m0 + arow) * DM + k0 + acg * 4];
    As[acg * 4 + 0][arow] = av.x;
    As[acg * 4 + 1][arow] = av.y;
    As[acg * 4 + 2][arow] = av.z;
    As[acg * 4 + 3][arow] = av.w;
    #pragma unroll
    for (int p = 0; p < 4; ++p) {
      int fidx = tid + 256 * p;   // 0..1023
      int br = fidx >> 5, bc = fidx & 31;
      *(float4*)&Bs[br][bc * 4] = *(const float4*)&Win[(size_t)(k0 + br) * 128 + bc * 4];
    }
    __syncthreads();
    #pragma unroll
    for (int kk = 0; kk < 32; ++kk) {
      float4 a  = *(const float4*)&As[kk][ty4];
      float4 bb = *(const float4*)&Bs[kk][tx4];
      const float aa[4] = {a.x, a.y, a.z, a.w};
      const float bv[4] = {bb.x, bb.y, bb.z, bb.w};
      #pragma unroll
      for (int i = 0; i < 4; ++i)
        #pragma unroll
        for (int j = 0; j < 4; ++j)
          acc[i][j] = fmaf(aa[i], bv[j], acc[i][j]);
    }
    __syncthreads();
  }
  const int b  = m0 >> 11;
  const int l0 = (m0 & 2047) + ty4;
  if (tx4 < 64) {
    #pragma unroll
    for (int i = 0; i < 4; ++i)
      *(float4*)&xp_pre[(size_t)(m0 + ty4 + i) * 64 + tx4] =
          make_float4(acc[i][0], acc[i][1], acc[i][2], acc[i][3]);
  } else {
    #pragma unroll
    for (int j = 0; j < 4; ++j) {
      int c = tx4 + j - 64;
      *(float4*)&resT[(size_t)(b * 64 + c) * L_ + l0] =
          make_float4(acc[0][j], acc[1][j], acc[2][j], acc[3][j]);
    }
  }
}

// ---- K2: fused conv+silu -> xpT ; [delta|B|C] = xp @ WF ; softplus(delta + b_dt) -> deltaT
// block = 64 tokens, 256 threads
__global__ __launch_bounds__(256) void k_fused(
    const float* __restrict__ xp_pre,
    const float* __restrict__ conv_w, const float* __restrict__ conv_b,
    const float* __restrict__ WF, const float* __restrict__ bdt,
    float* __restrict__ xpT, float* __restrict__ deltaT,
    float* __restrict__ Bm, float* __restrict__ Cm)
{
  __shared__ float raw[66][65];   // rows l0-2..l0+63 of xp_pre, then silu'd xp in rows 0..63
  __shared__ float Wh[32][192];   // one K-half of WF
  const int tid = threadIdx.x;
  const int t0 = blockIdx.x * 64;
  const int b  = t0 >> 11;
  const int l0 = t0 & 2047;
  // stage raw (zero-pad l<0)
  for (int fidx = tid; fidx < 66 * 16; fidx += 256) {
    int r = fidx >> 4, cg = fidx & 15;
    int l = l0 - 2 + r;
    float4 v = make_float4(0.f, 0.f, 0.f, 0.f);
    if (l >= 0) v = *(const float4*)&xp_pre[((size_t)b * L_ + l) * 64 + cg * 4];
    raw[r][cg * 4 + 0] = v.x;
    raw[r][cg * 4 + 1] = v.y;
    raw[r][cg * 4 + 2] = v.z;
    raw[r][cg * 4 + 3] = v.w;
  }
  __syncthreads();
  // conv + silu: thread -> (e, 16 tokens)
  const int e  = tid & 63;
  const int tl = tid >> 6;        // 0..3
  const float w0 = conv_w[e * KC + 0], w1 = conv_w[e * KC + 1], w2 = conv_w[e * KC + 2];
  const float cb = conv_b[e];
  float cres[16];
  #pragma unroll
  for (int i = 0; i < 16; ++i) {
    int tok = tl * 16 + i;
    float a = cb;
    a = fmaf(raw[tok + 0][e], w0, a);
    a = fmaf(raw[tok + 1][e], w1, a);
    a = fmaf(raw[tok + 2][e], w2, a);
    cres[i] = a / (1.f + __expf(-a));   // silu
  }
  __syncthreads();
  #pragma unroll
  for (int i = 0; i < 16; ++i) raw[tl * 16 + i][e] = cres[i];
  #pragma unroll
  for (int i = 0; i < 16; i += 4)
    *(float4*)&xpT[(size_t)(b * 64 + e) * L_ + l0 + tl * 16 + i] =
        make_float4(cres[i], cres[i + 1], cres[i + 2], cres[i + 3]);
  __syncthreads();
  // GEMM 64x192, K=64 in two staged halves
  const int tg = tid >> 4;        // tokens tg*4..+3
  const int cg = tid & 15;        // cols cg*12..+11
  float acc[4][12] = {};
  for (int half = 0; half < 2; ++half) {
    for (int fidx = tid; fidx < 32 * 48; fidx += 256) {
      int r = fidx / 48, c4 = fidx % 48;
      *(float4*)&Wh[r][c4 * 4] = *(const float4*)&WF[(size_t)(half * 32 + r) * 192 + c4 * 4];
    }
    __syncthreads();
    #pragma unroll 8
    for (int kk = 0; kk < 32; ++kk) {
      float a_[4];
      #pragma unroll
      for (int i = 0; i < 4; ++i) a_[i] = raw[tg * 4 + i][half * 32 + kk];
      float w_[12];
      #pragma unroll
      for (int j = 0; j < 12; j += 4) {
        float4 wv = *(const float4*)&Wh[kk][cg * 12 + j];
        w_[j] = wv.x; w_[j + 1] = wv.y; w_[j + 2] = wv.z; w_[j + 3] = wv.w;
      }
      #pragma unroll
      for (int i = 0; i < 4; ++i)
        #pragma unroll
        for (int j = 0; j < 12; ++j)
          acc[i][j] = fmaf(a_[i], w_[j], acc[i][j]);
    }
    __syncthreads();
  }
  // epilogue
  const int lbase = l0 + tg * 4;
  #pragma unroll
  for (int j = 0; j < 12; ++j) {
    int c = cg * 12 + j;
    if (c < 64) {
      float bias = bdt[c];
      float d0 = acc[0][j] + bias, d1 = acc[1][j] + bias,
            d2 = acc[2][j] + bias, d3 = acc[3][j] + bias;
      float4 dv;
      dv.x = (d0 > 20.f) ? d0 : log1pf(__expf(d0));
      dv.y = (d1 > 20.f) ? d1 : log1pf(__expf(d1));
      dv.z = (d2 > 20.f) ? d2 : log1pf(__expf(d2));
      dv.w = (d3 > 20.f) ? d3 : log1pf(__expf(d3));
      *(float4*)&deltaT[(size_t)(b * 64 + c) * L_ + lbase] = dv;
    } else if (c < 128) {
      #pragma unroll
      for (int i = 0; i < 4; ++i)
        Bm[(size_t)(t0 + tg * 4 + i) * 64 + (c - 64)] = acc[i][j];
    } else {
      #pragma unroll
      for (int i = 0; i < 4; ++i)
        Cm[(size_t)(t0 + tg * 4 + i) * 64 + (c - 128)] = acc[i][j];
    }
  }
}

// ---- K3a: per-chunk summaries. block = (b,e,c), lane = h.
__global__ __launch_bounds__(64) void k_scan1(
    const float* __restrict__ deltaT, const float* __restrict__ xpT,
    const float* __restrict__ Bm, const float* __restrict__ A_log,
    float* __restrict__ Ssum, float* __restrict__ Pp)
{
  __shared__ float dbuf[64], xbuf[64];
  const int blk = blockIdx.x;
  const int c = blk & (NCH - 1);
  const int e = (blk >> 4) & 63;
  const int b = blk >> 10;
  const int h = threadIdx.x;
  const float A = -__expf(A_log[e * 64 + h]);
  const size_t beL = (size_t)(b * 64 + e) * L_;
  float s = 0.f, sd = 0.f;
  for (int sub = 0; sub < LC / 64; ++sub) {
    const int l0 = c * LC + sub * 64;
    __syncthreads();
    dbuf[h] = deltaT[beL + l0 + h];
    xbuf[h] = xpT[beL + l0 + h];
    __syncthreads();
    #pragma unroll 4
    for (int k = 0; k < 64; ++k) {
      float dlt = dbuf[k];
      float w = dlt * xbuf[k];
      float Bh = Bm[(size_t)(b * L_ + l0 + k) * 64 + h];
      float dA = __expf(dlt * A);
      s = fmaf(dA, s, w * Bh);
      sd += dlt;
    }
  }
  const size_t idx = (size_t)blk * 64 + h;
  Ssum[idx] = s;
  Pp[idx]   = __expf(A * sd);
}

// ---- K3b: compose chunk summaries -> entry state per chunk. block = (b,e), lane = h.
__global__ __launch_bounds__(64) void k_scan2(
    const float* __restrict__ Ssum, const float* __restrict__ Pp,
    float* __restrict__ Sin)
{
  const int blk = blockIdx.x;     // b*64 + e
  const int h = threadIdx.x;
  float s_in = 0.f;
  #pragma unroll
  for (int c = 0; c < NCH; ++c) {
    const size_t idx = ((size_t)blk * NCH + c) * 64 + h;
    Sin[idx] = s_in;
    s_in = fmaf(Pp[idx], s_in, Ssum[idx]);
  }
}

// ---- K3c: scan per chunk from entry state; bf16 LDS-transpose reduction for y.
__global__ __launch_bounds__(64) void k_scan3(
    const float* __restrict__ deltaT, const float* __restrict__ xpT,
    const float* __restrict__ resT,
    const float* __restrict__ Bm, const float* __restrict__ Cm,
    const float* __restrict__ A_log, const float* __restrict__ Dp,
    const float* __restrict__ Sin,
    float* __restrict__ yg)
{
  __shared__ unsigned short tile[64 * 68];   // bf16, 136B rows (8B aligned)
  __shared__ float dbuf[64], xbuf[64], rbuf[64];
  const int blk = blockIdx.x;
  const int c = blk & (NCH - 1);
  const int e = (blk >> 4) & 63;
  const int b = blk >> 10;
  const int h = threadIdx.x;
  const float A = -__expf(A_log[e * 64 + h]);
  const float Dv = Dp[e];
  const size_t beL = (size_t)(b * 64 + e) * L_;
  float s = Sin[(size_t)blk * 64 + h];
  for (int sub = 0; sub < LC / 64; ++sub) {
    const int l0 = c * LC + sub * 64;
    __syncthreads();
    dbuf[h] = deltaT[beL + l0 + h];
    xbuf[h] = xpT[beL + l0 + h];
    rbuf[h] = resT[beL + l0 + h];
    __syncthreads();
    #pragma unroll 4
    for (int k = 0; k < 64; ++k) {
      float dlt = dbuf[k];
      float w = dlt * xbuf[k];
      const size_t off = (size_t)(b * L_ + l0 + k) * 64;
      float Bh = Bm[off + h];
      float Ch = Cm[off + h];
      float dA = __expf(dlt * A);
      s = fmaf(dA, s, w * Bh);
      __hip_bfloat16 bv = __float2bfloat16(s * Ch);
      tile[k * 68 + h] = *reinterpret_cast<unsigned short*>(&bv);
    }
    __syncthreads();
    // lane h reduces row h (token l0+h) over 64 h-slots
    float a0 = 0.f, a1 = 0.f, a2 = 0.f, a3 = 0.f;
    const ushort4* rp = (const ushort4*)&tile[h * 68];
    #pragma unroll
    for (int q = 0; q < 16; ++q) {
      ushort4 u = rp[q];
      a0 += __uint_as_float((unsigned)u.x << 16);
      a1 += __uint_as_float((unsigned)u.y << 16);
      a2 += __uint_as_float((unsigned)u.z << 16);
      a3 += __uint_as_float((unsigned)u.w << 16);
    }
    float sum = (a0 + a1) + (a2 + a3);
    float y = fmaf(xbuf[h], Dv, sum);
    y *= 1.0f / (1.0f + __expf(-rbuf[h]));   // * sigmoid(res)
    yg[(size_t)(b * L_ + l0 + h) * 64 + e] = y;
  }
}

// ---- K4: out = yg @ W_out  (16384x64 @ 64x512), 4 tokens per block
__global__ __launch_bounds__(256) void k_gemm_out(
    const float* __restrict__ yg, const float* __restrict__ Wout,
    float* __restrict__ out)
{
  __shared__ float ys[4][64];
  const int t0 = blockIdx.x * 4;
  const int tid = threadIdx.x;
  {
    int t = tid >> 6, k = tid & 63;
    ys[t][k] = yg[(size_t)(t0 + t) * 64 + k];
  }
  __syncthreads();
  float acc[4][2] = {};
  for (int k = 0; k < 64; ++k) {
    float w0 = Wout[k * DM + tid];
    float w1 = Wout[k * DM + tid + 256];
    #pragma unroll
    for (int t = 0; t < 4; ++t) {
      acc[t][0] = fmaf(ys[t][k], w0, acc[t][0]);
      acc[t][1] = fmaf(ys[t][k], w1, acc[t][1]);
    }
  }
  #pragma unroll
  for (int t = 0; t < 4; ++t) {
    out[(size_t)(t0 + t) * DM + tid]       = acc[t][0];
    out[(size_t)(t0 + t) * DM + tid + 256] = acc[t][1];
  }
}

extern "C" void kernel_launch(void* const* d_in, const int* in_sizes, int n_in,
                              void* d_out, int out_size, void* d_ws, size_t ws_size,
                              hipStream_t stream) {
  const float* x      = (const float*)d_in[0];
  const float* Win    = (const float*)d_in[1];
  const float* conv_w = (const float*)d_in[2];
  const float* conv_b = (const float*)d_in[3];
  const float* Wx     = (const float*)d_in[4];
  const float* Wdt    = (const float*)d_in[5];
  const float* bdt    = (const float*)d_in[6];
  const float* A_log  = (const float*)d_in[7];
  const float* Dp     = (const float*)d_in[8];
  const float* Wout   = (const float*)d_in[9];
  float* out = (float*)d_out;

  float* ws = (float*)d_ws;
  const size_t SZ = (size_t)BL * 64;              // 1M floats
  const size_t CH = (size_t)B_ * E_ * NCH * 64;   // 512K floats
  float* xp_pre = ws + 0 * SZ;
  float* resT   = ws + 1 * SZ;
  float* xpT    = ws + 2 * SZ;
  float* deltaT = ws + 3 * SZ;
  float* Bm     = ws + 4 * SZ;
  float* Cm     = ws + 5 * SZ;
  float* yg     = ws + 6 * SZ;
  float* Ssum   = ws + 7 * SZ;
  float* Pp     = ws + 7 * SZ + 1 * CH;
  float* Sin    = ws + 7 * SZ + 2 * CH;
  float* WF     = ws + 7 * SZ + 3 * CH;           // 12288 floats

  hipLaunchKernelGGL(k_wfuse,    dim3(64),            dim3(192), 0, stream, Wx, Wdt, WF);
  hipLaunchKernelGGL(k_gemm_in,  dim3(BL / 32),       dim3(256), 0, stream, x, Win, xp_pre, resT);
  hipLaunchKernelGGL(k_fused,    dim3(BL / 64),       dim3(256), 0, stream,
                     xp_pre, conv_w, conv_b, WF, bdt, xpT, deltaT, Bm, Cm);
  hipLaunchKernelGGL(k_scan1,    dim3(B_ * E_ * NCH), dim3(64),  0, stream,
                     deltaT, xpT, Bm, A_log, Ssum, Pp);
  hipLaunchKernelGGL(k_scan2,    dim3(B_ * E_),       dim3(64),  0, stream, Ssum, Pp, Sin);
  hipLaunchKernelGGL(k_scan3,    dim3(B_ * E_ * NCH), dim3(64),  0, stream,
                     deltaT, xpT, resT, Bm, Cm, A_log, Dp, Sin, yg);
  hipLaunchKernelGGL(k_gemm_out, dim3(BL / 4),        dim3(256), 0, stream, yg, Wout, out);
}

// Round 7
// 214.745 us; speedup vs baseline: 7.5467x; 1.1372x over previous
//
#include <hip/hip_runtime.h>
#include <hip/hip_bf16.h>

#define B_ 8
#define L_ 2048
#define DM 512
#define E_ 64
#define H_ 64
#define R_ 4
#define KC 3
#define BL (B_*L_)   // 16384
#define NX 132       // R + 2H
#define LC 128       // scan chunk length
#define NCH (L_/LC)  // 16 chunks

typedef __attribute__((ext_vector_type(8))) short bfrag;
typedef __attribute__((ext_vector_type(4))) float facc;

__device__ __forceinline__ unsigned short f2b(float f) {
  __hip_bfloat16 h = __float2bfloat16(f);
  return *reinterpret_cast<unsigned short*>(&h);
}
__device__ __forceinline__ bfrag ld_frag(const unsigned short* p) {
  bfrag t;
  __builtin_memcpy(&t, p, 16);   // 16B-aligned LDS rows -> ds_read_b128
  return t;
}

// ---- K0: fold W_dt into W_x -> WF[64][192]
__global__ __launch_bounds__(192) void k_wfuse(
    const float* __restrict__ Wx, const float* __restrict__ Wdt,
    float* __restrict__ WF)
{
  const int r = blockIdx.x;
  const int c = threadIdx.x;
  float v;
  if (c < 64) {
    v = 0.f;
    #pragma unroll
    for (int j = 0; j < R_; ++j)
      v = fmaf(Wx[r * NX + j], Wdt[j * 64 + c], v);
  } else if (c < 128) {
    v = Wx[r * NX + R_ + (c - 64)];
  } else {
    v = Wx[r * NX + R_ + 64 + (c - 128)];
  }
  WF[r * 192 + c] = v;
}

// ---- K1 (MFMA, double-buffered LDS): xz = x @ W_in
// cols 0..63 -> xp_pre[token][64], 64..127 -> resT[(b*64+c)][L]
// BM=64, BN=128(full), BK=32. 256 blocks x 128 threads (2 waves).
__global__ __launch_bounds__(128) void k_gemm_in(
    const float* __restrict__ x, const float* __restrict__ Win,
    float* __restrict__ xp_pre, float* __restrict__ resT)
{
  __shared__ unsigned short As[2][64][36];    // 72 B rows (8B aligned)
  __shared__ unsigned short Bs[2][128][36];   // B transposed [n][k]
  const int tid  = threadIdx.x;
  const int m0   = blockIdx.x * 64;
  const int b    = m0 >> 11;
  const int l0   = m0 & 2047;
  const int lane = tid & 63;
  const int wave = tid >> 6;
  const int nl   = lane & 15;
  const int g    = lane >> 4;
  facc acc[2][8];
  #pragma unroll
  for (int i = 0; i < 2; ++i)
    #pragma unroll
    for (int j = 0; j < 8; ++j)
      acc[i][j] = (facc)(0.f);

  // staging helper: stage K-slab starting at k0 into buffer sel
  auto stage = [&](int sel, int k0) {
    #pragma unroll
    for (int p = 0; p < 4; ++p) {
      int fidx = tid + 128 * p;            // 0..511
      int r = fidx >> 3, q = fidx & 7;
      float4 v = *(const float4*)&x[(size_t)(m0 + r) * DM + k0 + 4 * q];
      ushort4 u;
      u.x = f2b(v.x); u.y = f2b(v.y); u.z = f2b(v.z); u.w = f2b(v.w);
      *(ushort4*)&As[sel][r][4 * q] = u;
    }
    #pragma unroll
    for (int p = 0; p < 8; ++p) {
      int fidx = tid + 128 * p;            // 0..1023
      int r = fidx >> 5, cq = fidx & 31;
      float4 v = *(const float4*)&Win[(size_t)(k0 + r) * 128 + 4 * cq];
      Bs[sel][4 * cq + 0][r] = f2b(v.x);
      Bs[sel][4 * cq + 1][r] = f2b(v.y);
      Bs[sel][4 * cq + 2][r] = f2b(v.z);
      Bs[sel][4 * cq + 3][r] = f2b(v.w);
    }
  };

  stage(0, 0);
  __syncthreads();
  for (int it = 0; it < 16; ++it) {
    const int cur = it & 1;
    if (it + 1 < 16) stage(cur ^ 1, (it + 1) * 32);   // write OTHER buffer: no WAR with cur readers
    bfrag af0 = ld_frag(&As[cur][wave * 32 + nl][g * 8]);
    bfrag af1 = ld_frag(&As[cur][wave * 32 + 16 + nl][g * 8]);
    #pragma unroll
    for (int nt = 0; nt < 8; ++nt) {
      bfrag bfr = ld_frag(&Bs[cur][nt * 16 + nl][g * 8]);
      acc[0][nt] = __builtin_amdgcn_mfma_f32_16x16x32_bf16(af0, bfr, acc[0][nt], 0, 0, 0);
      acc[1][nt] = __builtin_amdgcn_mfma_f32_16x16x32_bf16(af1, bfr, acc[1][nt], 0, 0, 0);
    }
    __syncthreads();   // RAW for next buffer; cur readers all done before its re-staging (2 its away)
  }
  // epilogue: D col = nl (tile nt), row = 4g + reg (tile mt)
  #pragma unroll
  for (int mt = 0; mt < 2; ++mt) {
    int mrow = wave * 32 + mt * 16 + 4 * g;
    #pragma unroll
    for (int nt = 0; nt < 8; ++nt) {
      facc a = acc[mt][nt];
      if (nt < 4) {
        int c = nt * 16 + nl;
        #pragma unroll
        for (int r = 0; r < 4; ++r)
          xp_pre[(size_t)(m0 + mrow + r) * 64 + c] = a[r];
      } else {
        int c = nt * 16 + nl - 64;
        *(float4*)&resT[(size_t)(b * 64 + c) * L_ + l0 + mrow] =
            make_float4(a[0], a[1], a[2], a[3]);
      }
    }
  }
}

// ---- K2: fused conv+silu -> xpT ; [delta|B|C] = xp @ WF ; softplus -> deltaT
__global__ __launch_bounds__(256) void k_fused(
    const float* __restrict__ xp_pre,
    const float* __restrict__ conv_w, const float* __restrict__ conv_b,
    const float* __restrict__ WF, const float* __restrict__ bdt,
    float* __restrict__ xpT, float* __restrict__ deltaT,
    float* __restrict__ Bm, float* __restrict__ Cm)
{
  __shared__ float raw[66][65];
  __shared__ float Wh[32][192];
  const int tid = threadIdx.x;
  const int t0 = blockIdx.x * 64;
  const int b  = t0 >> 11;
  const int l0 = t0 & 2047;
  for (int fidx = tid; fidx < 66 * 16; fidx += 256) {
    int r = fidx >> 4, cg = fidx & 15;
    int l = l0 - 2 + r;
    float4 v = make_float4(0.f, 0.f, 0.f, 0.f);
    if (l >= 0) v = *(const float4*)&xp_pre[((size_t)b * L_ + l) * 64 + cg * 4];
    raw[r][cg * 4 + 0] = v.x;
    raw[r][cg * 4 + 1] = v.y;
    raw[r][cg * 4 + 2] = v.z;
    raw[r][cg * 4 + 3] = v.w;
  }
  __syncthreads();
  const int e  = tid & 63;
  const int tl = tid >> 6;
  const float w0 = conv_w[e * KC + 0], w1 = conv_w[e * KC + 1], w2 = conv_w[e * KC + 2];
  const float cb = conv_b[e];
  float cres[16];
  #pragma unroll
  for (int i = 0; i < 16; ++i) {
    int tok = tl * 16 + i;
    float a = cb;
    a = fmaf(raw[tok + 0][e], w0, a);
    a = fmaf(raw[tok + 1][e], w1, a);
    a = fmaf(raw[tok + 2][e], w2, a);
    cres[i] = a / (1.f + __expf(-a));
  }
  __syncthreads();
  #pragma unroll
  for (int i = 0; i < 16; ++i) raw[tl * 16 + i][e] = cres[i];
  #pragma unroll
  for (int i = 0; i < 16; i += 4)
    *(float4*)&xpT[(size_t)(b * 64 + e) * L_ + l0 + tl * 16 + i] =
        make_float4(cres[i], cres[i + 1], cres[i + 2], cres[i + 3]);
  __syncthreads();
  const int tg = tid >> 4;
  const int cg = tid & 15;
  float acc[4][12] = {};
  for (int half = 0; half < 2; ++half) {
    for (int fidx = tid; fidx < 32 * 48; fidx += 256) {
      int r = fidx / 48, c4 = fidx % 48;
      *(float4*)&Wh[r][c4 * 4] = *(const float4*)&WF[(size_t)(half * 32 + r) * 192 + c4 * 4];
    }
    __syncthreads();
    #pragma unroll 8
    for (int kk = 0; kk < 32; ++kk) {
      float a_[4];
      #pragma unroll
      for (int i = 0; i < 4; ++i) a_[i] = raw[tg * 4 + i][half * 32 + kk];
      float w_[12];
      #pragma unroll
      for (int j = 0; j < 12; j += 4) {
        float4 wv = *(const float4*)&Wh[kk][cg * 12 + j];
        w_[j] = wv.x; w_[j + 1] = wv.y; w_[j + 2] = wv.z; w_[j + 3] = wv.w;
      }
      #pragma unroll
      for (int i = 0; i < 4; ++i)
        #pragma unroll
        for (int j = 0; j < 12; ++j)
          acc[i][j] = fmaf(a_[i], w_[j], acc[i][j]);
    }
    __syncthreads();
  }
  const int lbase = l0 + tg * 4;
  #pragma unroll
  for (int j = 0; j < 12; ++j) {
    int c = cg * 12 + j;
    if (c < 64) {
      float bias = bdt[c];
      float d0 = acc[0][j] + bias, d1 = acc[1][j] + bias,
            d2 = acc[2][j] + bias, d3 = acc[3][j] + bias;
      float4 dv;
      dv.x = (d0 > 20.f) ? d0 : log1pf(__expf(d0));
      dv.y = (d1 > 20.f) ? d1 : log1pf(__expf(d1));
      dv.z = (d2 > 20.f) ? d2 : log1pf(__expf(d2));
      dv.w = (d3 > 20.f) ? d3 : log1pf(__expf(d3));
      *(float4*)&deltaT[(size_t)(b * 64 + c) * L_ + lbase] = dv;
    } else if (c < 128) {
      #pragma unroll
      for (int i = 0; i < 4; ++i)
        Bm[(size_t)(t0 + tg * 4 + i) * 64 + (c - 64)] = acc[i][j];
    } else {
      #pragma unroll
      for (int i = 0; i < 4; ++i)
        Cm[(size_t)(t0 + tg * 4 + i) * 64 + (c - 128)] = acc[i][j];
    }
  }
}

// ---- K3a: per-chunk summaries
__global__ __launch_bounds__(64) void k_scan1(
    const float* __restrict__ deltaT, const float* __restrict__ xpT,
    const float* __restrict__ Bm, const float* __restrict__ A_log,
    float* __restrict__ Ssum, float* __restrict__ Pp)
{
  __shared__ float dbuf[64], xbuf[64];
  const int blk = blockIdx.x;
  const int c = blk & (NCH - 1);
  const int e = (blk >> 4) & 63;
  const int b = blk >> 10;
  const int h = threadIdx.x;
  const float A = -__expf(A_log[e * 64 + h]);
  const size_t beL = (size_t)(b * 64 + e) * L_;
  float s = 0.f, sd = 0.f;
  for (int sub = 0; sub < LC / 64; ++sub) {
    const int l0 = c * LC + sub * 64;
    __syncthreads();
    dbuf[h] = deltaT[beL + l0 + h];
    xbuf[h] = xpT[beL + l0 + h];
    __syncthreads();
    #pragma unroll 4
    for (int k = 0; k < 64; ++k) {
      float dlt = dbuf[k];
      float w = dlt * xbuf[k];
      float Bh = Bm[(size_t)(b * L_ + l0 + k) * 64 + h];
      float dA = __expf(dlt * A);
      s = fmaf(dA, s, w * Bh);
      sd += dlt;
    }
  }
  const size_t idx = (size_t)blk * 64 + h;
  Ssum[idx] = s;
  Pp[idx]   = __expf(A * sd);
}

// ---- K3b: compose chunk summaries
__global__ __launch_bounds__(64) void k_scan2(
    const float* __restrict__ Ssum, const float* __restrict__ Pp,
    float* __restrict__ Sin)
{
  const int blk = blockIdx.x;
  const int h = threadIdx.x;
  float s_in = 0.f;
  #pragma unroll
  for (int c = 0; c < NCH; ++c) {
    const size_t idx = ((size_t)blk * NCH + c) * 64 + h;
    Sin[idx] = s_in;
    s_in = fmaf(Pp[idx], s_in, Ssum[idx]);
  }
}

// ---- K3c: scan per chunk; bf16 LDS-transpose reduction
__global__ __launch_bounds__(64) void k_scan3(
    const float* __restrict__ deltaT, const float* __restrict__ xpT,
    const float* __restrict__ resT,
    const float* __restrict__ Bm, const float* __restrict__ Cm,
    const float* __restrict__ A_log, const float* __restrict__ Dp,
    const float* __restrict__ Sin,
    float* __restrict__ yg)
{
  __shared__ unsigned short tile[64 * 68];
  __shared__ float dbuf[64], xbuf[64], rbuf[64];
  const int blk = blockIdx.x;
  const int c = blk & (NCH - 1);
  const int e = (blk >> 4) & 63;
  const int b = blk >> 10;
  const int h = threadIdx.x;
  const float A = -__expf(A_log[e * 64 + h]);
  const float Dv = Dp[e];
  const size_t beL = (size_t)(b * 64 + e) * L_;
  float s = Sin[(size_t)blk * 64 + h];
  for (int sub = 0; sub < LC / 64; ++sub) {
    const int l0 = c * LC + sub * 64;
    __syncthreads();
    dbuf[h] = deltaT[beL + l0 + h];
    xbuf[h] = xpT[beL + l0 + h];
    rbuf[h] = resT[beL + l0 + h];
    __syncthreads();
    #pragma unroll 4
    for (int k = 0; k < 64; ++k) {
      float dlt = dbuf[k];
      float w = dlt * xbuf[k];
      const size_t off = (size_t)(b * L_ + l0 + k) * 64;
      float Bh = Bm[off + h];
      float Ch = Cm[off + h];
      float dA = __expf(dlt * A);
      s = fmaf(dA, s, w * Bh);
      __hip_bfloat16 bv = __float2bfloat16(s * Ch);
      tile[k * 68 + h] = *reinterpret_cast<unsigned short*>(&bv);
    }
    __syncthreads();
    float a0 = 0.f, a1 = 0.f, a2 = 0.f, a3 = 0.f;
    const ushort4* rp = (const ushort4*)&tile[h * 68];
    #pragma unroll
    for (int q = 0; q < 16; ++q) {
      ushort4 u = rp[q];
      a0 += __uint_as_float((unsigned)u.x << 16);
      a1 += __uint_as_float((unsigned)u.y << 16);
      a2 += __uint_as_float((unsigned)u.z << 16);
      a3 += __uint_as_float((unsigned)u.w << 16);
    }
    float sum = (a0 + a1) + (a2 + a3);
    float y = fmaf(xbuf[h], Dv, sum);
    y *= 1.0f / (1.0f + __expf(-rbuf[h]));
    yg[(size_t)(b * L_ + l0 + h) * 64 + e] = y;
  }
}

// ---- K4 (MFMA): out = yg @ W_out. BM=64, BN=128, K=64 single stage. 1024 blocks x 128 thr.
__global__ __launch_bounds__(128) void k_gemm_out(
    const float* __restrict__ yg, const float* __restrict__ Wout,
    float* __restrict__ out)
{
  __shared__ unsigned short As[64][68];    // 136 B rows
  __shared__ unsigned short Bs[128][68];   // Wout transposed [n][k]
  const int tid  = threadIdx.x;
  const int m0   = (blockIdx.x & 255) * 64;
  const int n0   = (blockIdx.x >> 8) * 128;
  const int lane = tid & 63;
  const int wave = tid >> 6;
  const int nl   = lane & 15;
  const int g    = lane >> 4;
  #pragma unroll
  for (int p = 0; p < 8; ++p) {
    int fidx = tid + 128 * p;              // 0..1023
    int r = fidx >> 4, q = fidx & 15;
    float4 v = *(const float4*)&yg[(size_t)(m0 + r) * 64 + 4 * q];
    ushort4 u;
    u.x = f2b(v.x); u.y = f2b(v.y); u.z = f2b(v.z); u.w = f2b(v.w);
    *(ushort4*)&As[r][4 * q] = u;
  }
  #pragma unroll
  for (int p = 0; p < 16; ++p) {
    int fidx = tid + 128 * p;              // 0..2047
    int r = fidx >> 5, cq = fidx & 31;
    float4 v = *(const float4*)&Wout[(size_t)r * DM + n0 + 4 * cq];
    Bs[4 * cq + 0][r] = f2b(v.x);
    Bs[4 * cq + 1][r] = f2b(v.y);
    Bs[4 * cq + 2][r] = f2b(v.z);
    Bs[4 * cq + 3][r] = f2b(v.w);
  }
  __syncthreads();
  facc acc[2][8];
  #pragma unroll
  for (int i = 0; i < 2; ++i)
    #pragma unroll
    for (int j = 0; j < 8; ++j)
      acc[i][j] = (facc)(0.f);
  #pragma unroll
  for (int ks = 0; ks < 2; ++ks) {
    bfrag af0 = ld_frag(&As[wave * 32 + nl][ks * 32 + g * 8]);
    bfrag af1 = ld_frag(&As[wave * 32 + 16 + nl][ks * 32 + g * 8]);
    #pragma unroll
    for (int nt = 0; nt < 8; ++nt) {
      bfrag bfr = ld_frag(&Bs[nt * 16 + nl][ks * 32 + g * 8]);
      acc[0][nt] = __builtin_amdgcn_mfma_f32_16x16x32_bf16(af0, bfr, acc[0][nt], 0, 0, 0);
      acc[1][nt] = __builtin_amdgcn_mfma_f32_16x16x32_bf16(af1, bfr, acc[1][nt], 0, 0, 0);
    }
  }
  #pragma unroll
  for (int mt = 0; mt < 2; ++mt) {
    int mrow = m0 + wave * 32 + mt * 16 + 4 * g;
    #pragma unroll
    for (int nt = 0; nt < 8; ++nt) {
      facc a = acc[mt][nt];
      int c = n0 + nt * 16 + nl;
      #pragma unroll
      for (int r = 0; r < 4; ++r)
        out[(size_t)(mrow + r) * DM + c] = a[r];
    }
  }
}

extern "C" void kernel_launch(void* const* d_in, const int* in_sizes, int n_in,
                              void* d_out, int out_size, void* d_ws, size_t ws_size,
                              hipStream_t stream) {
  const float* x      = (const float*)d_in[0];
  const float* Win    = (const float*)d_in[1];
  const float* conv_w = (const float*)d_in[2];
  const float* conv_b = (const float*)d_in[3];
  const float* Wx     = (const float*)d_in[4];
  const float* Wdt    = (const float*)d_in[5];
  const float* bdt    = (const float*)d_in[6];
  const float* A_log  = (const float*)d_in[7];
  const float* Dp     = (const float*)d_in[8];
  const float* Wout   = (const float*)d_in[9];
  float* out = (float*)d_out;

  float* ws = (float*)d_ws;
  const size_t SZ = (size_t)BL * 64;
  const size_t CH = (size_t)B_ * E_ * NCH * 64;
  float* xp_pre = ws + 0 * SZ;
  float* resT   = ws + 1 * SZ;
  float* xpT    = ws + 2 * SZ;
  float* deltaT = ws + 3 * SZ;
  float* Bm     = ws + 4 * SZ;
  float* Cm     = ws + 5 * SZ;
  float* yg     = ws + 6 * SZ;
  float* Ssum   = ws + 7 * SZ;
  float* Pp     = ws + 7 * SZ + 1 * CH;
  float* Sin    = ws + 7 * SZ + 2 * CH;
  float* WF     = ws + 7 * SZ + 3 * CH;

  hipLaunchKernelGGL(k_wfuse,    dim3(64),            dim3(192), 0, stream, Wx, Wdt, WF);
  hipLaunchKernelGGL(k_gemm_in,  dim3(BL / 64),       dim3(128), 0, stream, x, Win, xp_pre, resT);
  hipLaunchKernelGGL(k_fused,    dim3(BL / 64),       dim3(256), 0, stream,
                     xp_pre, conv_w, conv_b, WF, bdt, xpT, deltaT, Bm, Cm);
  hipLaunchKernelGGL(k_scan1,    dim3(B_ * E_ * NCH), dim3(64),  0, stream,
                     deltaT, xpT, Bm, A_log, Ssum, Pp);
  hipLaunchKernelGGL(k_scan2,    dim3(B_ * E_),       dim3(64),  0, stream, Ssum, Pp, Sin);
  hipLaunchKernelGGL(k_scan3,    dim3(B_ * E_ * NCH), dim3(64),  0, stream,
                     deltaT, xpT, resT, Bm, Cm, A_log, Dp, Sin, yg);
  hipLaunchKernelGGL(k_gemm_out, dim3(1024),          dim3(128), 0, stream, yg, Wout, out);
}